// Round 6
// baseline (3943.358 us; speedup 1.0000x reference)
//
#include <hip/hip_runtime.h>

namespace {

constexpr int H   = 64;
constexpr int NIN = 21;
constexpr int T   = 3000;
constexpr int NB  = 2;     // batches per block
constexpr int G   = 256;   // 4*H

__device__ __forceinline__ float sigm(float v) {
    return 1.0f / (1.0f + __expf(-v));
}
__device__ __forceinline__ float tanh_fast(float v) {
    float e = __expf(2.0f * v);
    return 1.0f - 2.0f / (e + 1.0f);
}

// One MAC = one VOP2 v_fmac_f32 with DPP row_ror on src0 (the h operand).
// HW: row_ror:J delivers in[(lane & 48) | ((lane - J) & 15)] — matches the
// (lane - j) & 15 weight gather (verified passing in rounds 3-5).
#define FMAC0(A, Hv, Wv) \
    asm("v_fmac_f32 %0, %2, %3" : "=v"(A) : "0"(A), "v"(Hv), "v"(Wv))
#define FMACJ(A, Hv, Wv, J) \
    asm("v_fmac_f32 %0, %2, %3 row_ror:" #J : "=v"(A) : "0"(A), "v"(Hv), "v"(Wv))

// 16-term rotated dot for both batches; 4 accumulator chains (even/odd J x batch)
#define DOT16(W, OFS, H0, H1, A0E, A0O, A1E, A1O) do {            \
    FMAC0(A0E, H0, W[OFS + 0]);      FMAC0(A1E, H1, W[OFS + 0]);  \
    FMACJ(A0O, H0, W[OFS + 1], 1);   FMACJ(A1O, H1, W[OFS + 1], 1);\
    FMACJ(A0E, H0, W[OFS + 2], 2);   FMACJ(A1E, H1, W[OFS + 2], 2);\
    FMACJ(A0O, H0, W[OFS + 3], 3);   FMACJ(A1O, H1, W[OFS + 3], 3);\
    FMACJ(A0E, H0, W[OFS + 4], 4);   FMACJ(A1E, H1, W[OFS + 4], 4);\
    FMACJ(A0O, H0, W[OFS + 5], 5);   FMACJ(A1O, H1, W[OFS + 5], 5);\
    FMACJ(A0E, H0, W[OFS + 6], 6);   FMACJ(A1E, H1, W[OFS + 6], 6);\
    FMACJ(A0O, H0, W[OFS + 7], 7);   FMACJ(A1O, H1, W[OFS + 7], 7);\
    FMACJ(A0E, H0, W[OFS + 8], 8);   FMACJ(A1E, H1, W[OFS + 8], 8);\
    FMACJ(A0O, H0, W[OFS + 9], 9);   FMACJ(A1O, H1, W[OFS + 9], 9);\
    FMACJ(A0E, H0, W[OFS + 10], 10); FMACJ(A1E, H1, W[OFS + 10], 10);\
    FMACJ(A0O, H0, W[OFS + 11], 11); FMACJ(A1O, H1, W[OFS + 11], 11);\
    FMACJ(A0E, H0, W[OFS + 12], 12); FMACJ(A1E, H1, W[OFS + 12], 12);\
    FMACJ(A0O, H0, W[OFS + 13], 13); FMACJ(A1O, H1, W[OFS + 13], 13);\
    FMACJ(A0E, H0, W[OFS + 14], 14); FMACJ(A1E, H1, W[OFS + 14], 14);\
    FMACJ(A0O, H0, W[OFS + 15], 15); FMACJ(A1O, H1, W[OFS + 15], 15);\
} while (0)

// 512 threads = 8 waves = 2 waves/SIMD -> per-wave unified-reg budget is
// 512/2 = 256: enough to keep all per-lane weights in ARCH VGPRs (the
// 768-thread variant forced a 170-reg budget and pushed weights to AGPRs,
// adding a v_accvgpr_read per MAC).
__launch_bounds__(512, 2)
__global__ void lstm_dpp(const float* __restrict__ x,
                         const float* __restrict__ Wih0, const float* __restrict__ Whh0,
                         const float* __restrict__ bih0, const float* __restrict__ bhh0,
                         const float* __restrict__ Wih1, const float* __restrict__ Whh1,
                         const float* __restrict__ bih1, const float* __restrict__ bhh1,
                         const float* __restrict__ Wfc,  const float* __restrict__ bfc,
                         float* __restrict__ out)
{
    const int tid  = threadIdx.x;
    const int lane = tid & 63;
    const int wid  = tid >> 6;
    const int b0   = blockIdx.x * NB;

    // roles: waves 0-3 = layer0 (Wih0+Whh0), waves 4-7 = layer1 (Wih1+Whh1).
    // pointwise: waves 0,1 -> layer0 (b=wid); waves 6,7 -> layer1 (b=wid-6).
    // x staging: waves 2,3 (b=wid-2).
    const bool isA = (wid < 4);
    const int  g   = tid & 255;        // gate row within role

    __shared__ float xs[4][NB][32];    // x staged 2 steps ahead, padded 21->32
    __shared__ float a0s[NB][G];       // layer0 pre-activations
    __shared__ float a1s[NB][G];       // layer1 pre-activations (full)
    __shared__ float h1s[NB][H];
    __shared__ float h2s[NB][H];

    // ---- per-lane weight gather, permuted for the DPP access pattern ----
    // slot J must hold rowW[16m + ((lane - J) & 15)]  (row_ror semantics)
    float wH[64];   // A: Whh0 row | B: Wih1 row
    float wG[64];   // B only: Whh1 row
    float wX[32];   // A only: Wih0 row, zero-padded 21->32
    float bias;
    if (isA) {
        const float* rowH = Whh0 + g * 64;
        #pragma unroll
        for (int m = 0; m < 4; ++m)
            #pragma unroll
            for (int j = 0; j < 16; ++j)
                wH[m * 16 + j] = rowH[16 * m + ((lane - j) & 15)];
        #pragma unroll
        for (int m = 0; m < 2; ++m)
            #pragma unroll
            for (int j = 0; j < 16; ++j) {
                int k = 16 * m + ((lane - j) & 15);
                wX[m * 16 + j] = (k < NIN) ? Wih0[g * NIN + k] : 0.0f;
            }
        #pragma unroll
        for (int i = 0; i < 64; ++i) wG[i] = 0.0f;
        bias = bih0[g] + bhh0[g];
    } else {
        const float* rowB = Wih1 + g * 64;
        const float* rowC = Whh1 + g * 64;
        #pragma unroll
        for (int m = 0; m < 4; ++m)
            #pragma unroll
            for (int j = 0; j < 16; ++j) {
                wH[m * 16 + j] = rowB[16 * m + ((lane - j) & 15)];
                wG[m * 16 + j] = rowC[16 * m + ((lane - j) & 15)];
            }
        #pragma unroll
        for (int i = 0; i < 32; ++i) wX[i] = 0.0f;
        bias = bih1[g] + bhh1[g];
    }

    // zero h buffers; stage x(0) and x(1) (staging thread writes the pad too,
    // so no separate zeroing pass / no write race)
    if (tid < 128) {
        (&h1s[0][0])[tid] = 0.0f;
        (&h2s[0][0])[tid] = 0.0f;
    }
    if (isA && lane < 32) {
        const int s = (wid < 2) ? 1 : 0;      // waves 0,1 -> t=1; waves 2,3 -> t=0
        const int b = wid & 1;
        float v = 0.0f;
        if (lane < NIN) v = x[((size_t)(b0 + b) * T + s) * NIN + lane];
        xs[s][b][lane] = v;
    }

    float hq1[NB][4];   // h1 replicated: hq1[b][m] = h1[b][16m + (lane&15)]
    float hq2[NB][4];   // h2 replicated (used by B-waves only)
    #pragma unroll
    for (int b = 0; b < NB; ++b)
        #pragma unroll
        for (int m = 0; m < 4; ++m) { hq1[b][m] = 0.0f; hq2[b][m] = 0.0f; }

    float c_st = 0.0f;  // c1 on waves 0,1 ; c2 on waves 6,7
    __syncthreads();

    // Pipeline: iteration t computes layer0(t) and layer1(t-1).
    for (int t = 0; t <= T; ++t) {
        // ---------------- phase 1: matvec FMAs ----------------
        if (isA) {
            // stage x(t+2) early (waves 2,3); LDS-write after the FMAs
            float xv = 0.0f;
            const bool st = (wid >= 2) && (t + 2 < T) && (lane < 32);
            if (st && lane < NIN)
                xv = x[((size_t)(b0 + (wid - 2)) * T + (t + 2)) * NIN + lane];
            if (t < T) {
                float xq00 = xs[t & 3][0][lane & 15];
                float xq01 = xs[t & 3][0][16 + (lane & 15)];
                float xq10 = xs[t & 3][1][lane & 15];
                float xq11 = xs[t & 3][1][16 + (lane & 15)];
                float a0e = bias, a0o = 0.0f, a1e = bias, a1o = 0.0f;
                DOT16(wH, 0,  hq1[0][0], hq1[1][0], a0e, a0o, a1e, a1o);
                DOT16(wH, 16, hq1[0][1], hq1[1][1], a0e, a0o, a1e, a1o);
                DOT16(wH, 32, hq1[0][2], hq1[1][2], a0e, a0o, a1e, a1o);
                DOT16(wH, 48, hq1[0][3], hq1[1][3], a0e, a0o, a1e, a1o);
                DOT16(wX, 0,  xq00,      xq10,      a0e, a0o, a1e, a1o);
                DOT16(wX, 16, xq01,      xq11,      a0e, a0o, a1e, a1o);
                a0s[0][g] = a0e + a0o;
                a0s[1][g] = a1e + a1o;
            }
            if (st) xs[(t + 2) & 3][wid - 2][lane] = xv;
        } else {
            if (t > 0) {
                float a0e = bias, a0o = 0.0f, a1e = bias, a1o = 0.0f;
                DOT16(wH, 0,  hq1[0][0], hq1[1][0], a0e, a0o, a1e, a1o);
                DOT16(wH, 16, hq1[0][1], hq1[1][1], a0e, a0o, a1e, a1o);
                DOT16(wH, 32, hq1[0][2], hq1[1][2], a0e, a0o, a1e, a1o);
                DOT16(wH, 48, hq1[0][3], hq1[1][3], a0e, a0o, a1e, a1o);
                DOT16(wG, 0,  hq2[0][0], hq2[1][0], a0e, a0o, a1e, a1o);
                DOT16(wG, 16, hq2[0][1], hq2[1][1], a0e, a0o, a1e, a1o);
                DOT16(wG, 32, hq2[0][2], hq2[1][2], a0e, a0o, a1e, a1o);
                DOT16(wG, 48, hq2[0][3], hq2[1][3], a0e, a0o, a1e, a1o);
                a1s[0][g] = a0e + a0o;
                a1s[1][g] = a1e + a1o;
            }
        }
        __syncthreads();

        // ---------------- phase 2: pointwise (one wave per SIMD) ----------------
        if (wid <= 1) {
            if (t < T) {                       // layer0 step t, b = wid
                const int b = wid;
                const int u = lane;
                float gi = a0s[b][u];
                float gf = a0s[b][64 + u];
                float gg = a0s[b][128 + u];
                float go = a0s[b][192 + u];
                float i_ = sigm(gi), f_ = sigm(gf), g_ = tanh_fast(gg), o_ = sigm(go);
                c_st = fmaf(f_, c_st, i_ * g_);
                h1s[b][u] = o_ * tanh_fast(c_st);
            }
        } else if (wid >= 6) {
            if (t > 0) {                       // layer1 step t-1, b = wid-6
                const int b = wid - 6;
                const int u = lane;
                float gi = a1s[b][u];
                float gf = a1s[b][64 + u];
                float gg = a1s[b][128 + u];
                float go = a1s[b][192 + u];
                float i_ = sigm(gi), f_ = sigm(gf), g_ = tanh_fast(gg), o_ = sigm(go);
                c_st = fmaf(f_, c_st, i_ * g_);
                h2s[b][u] = o_ * tanh_fast(c_st);
            }
        }
        __syncthreads();

        if (t == T) break;

        // ---------------- phase 3: redistribute h into rotation registers ----------------
        #pragma unroll
        for (int b = 0; b < NB; ++b)
            #pragma unroll
            for (int m = 0; m < 4; ++m)
                hq1[b][m] = h1s[b][16 * m + (lane & 15)];
        if (!isA) {
            #pragma unroll
            for (int b = 0; b < NB; ++b)
                #pragma unroll
                for (int m = 0; m < 4; ++m)
                    hq2[b][m] = h2s[b][16 * m + (lane & 15)];
        }
    }

    // ---------------- FC epilogue: out[b] = dot(h2, Wfc) + bfc ----------------
    if (tid < 128) {
        const int b = tid >> 6;
        float v = h2s[b][lane] * Wfc[lane];
        #pragma unroll
        for (int off = 32; off > 0; off >>= 1)
            v += __shfl_down(v, off, 64);
        if (lane == 0) out[b0 + b] = v + bfc[0];
    }
}

} // namespace

extern "C" void kernel_launch(void* const* d_in, const int* in_sizes, int n_in,
                              void* d_out, int out_size, void* d_ws, size_t ws_size,
                              hipStream_t stream)
{
    const float* x    = (const float*)d_in[0];
    const float* Wih0 = (const float*)d_in[1];
    const float* Whh0 = (const float*)d_in[2];
    const float* bih0 = (const float*)d_in[3];
    const float* bhh0 = (const float*)d_in[4];
    const float* Wih1 = (const float*)d_in[5];
    const float* Whh1 = (const float*)d_in[6];
    const float* bih1 = (const float*)d_in[7];
    const float* bhh1 = (const float*)d_in[8];
    const float* Wfc  = (const float*)d_in[9];
    const float* bfc  = (const float*)d_in[10];
    float* out = (float*)d_out;

    hipLaunchKernelGGL(lstm_dpp, dim3(512 / NB), dim3(512), 0, stream,
                       x, Wih0, Whh0, bih0, bhh0, Wih1, Whh1, bih1, bhh1,
                       Wfc, bfc, out);
}